// Round 2
// baseline (472.009 us; speedup 1.0000x reference)
//
#include <hip/hip_runtime.h>

#define HH 256
#define WW 256
#define CC 64
#define BB 2
#define KK2 9
#define CG 16          // channels per main-kernel block (4 float4s)
#define HWSZ (HH * WW)

// ---------------- transpose: x[b][c][h][w] -> xT[b][h][w][c] ----------------
// grid (B*H, W/64), block 256. LDS 64x65 tile over (c, w).
__global__ __launch_bounds__(256, 4) void transpose_nchw_to_nhwc(
    const float* __restrict__ x, float* __restrict__ xT)
{
    __shared__ float tile[CC][65];
    const int row = blockIdx.x;
    const int h   = row & (HH - 1);
    const int b   = row >> 8;
    const int w0  = blockIdx.y * 64;
    const int lw  = threadIdx.x & 63;   // 0..63
    const int lr  = threadIdx.x >> 6;   // 0..3

    const float* xp = x + (size_t)b * CC * HWSZ + h * WW + w0;
#pragma unroll
    for (int p = 0; p < 16; ++p) {
        int c = p * 4 + lr;
        tile[c][lw] = xp[(size_t)c * HWSZ + lw];
    }
    __syncthreads();
    float* xo = xT + ((size_t)(b * HH + h) * WW + w0) * CC;
#pragma unroll
    for (int p = 0; p < 16; ++p) {
        int wl = p * 4 + lr;
        xo[wl * CC + lw] = tile[lw][wl];
    }
}

// ---------------- main: gather from NHWC ----------------
// grid (B*H, C/CG), block 256 (one output row per block).
__global__ __launch_bounds__(256, 4) void dcn_nhwc(
    const float4* __restrict__ xT,     // [B][H][W][C/4] float4
    const float* __restrict__ offset,
    const float* __restrict__ mask,
    const float* __restrict__ weight,
    float* __restrict__ out)
{
    const int w   = threadIdx.x;
    const int row = blockIdx.x;
    const int h   = row & (HH - 1);
    const int b   = row >> 8;
    const int cq  = blockIdx.y * (CG / 4);    // float4 index of channel base
    const int hw  = h * WW + w;

    const float* offb  = offset + (size_t)b * 2 * KK2 * HWSZ + hw;
    const float* maskb = mask   + (size_t)b * KK2 * HWSZ + hw;
    const float4* xb   = xT + (size_t)b * HWSZ * (CC / 4) + cq;

    float4 acc[CG / 4];
#pragma unroll
    for (int j = 0; j < CG / 4; ++j) acc[j] = make_float4(0.f, 0.f, 0.f, 0.f);

    for (int k = 0; k < KK2; ++k) {
        const int ki = k / 3;
        const int kj = k - 3 * ki;
        float offy = offb[(2 * k)     * HWSZ];
        float offx = offb[(2 * k + 1) * HWSZ];
        float mval = maskb[k * HWSZ] * weight[k];

        float py = (float)(h - 1 + ki) + offy;
        float px = (float)(w - 1 + kj) + offx;
        float y0f = floorf(py), x0f = floorf(px);
        float ly = py - y0f, lx = px - x0f;
        float hy = 1.f - ly, hx = 1.f - lx;
        int y0 = (int)y0f, x0 = (int)x0f;
        int y1 = y0 + 1,   x1 = x0 + 1;

        bool vy0 = (unsigned)y0 < (unsigned)HH;
        bool vy1 = (unsigned)y1 < (unsigned)HH;
        bool vx0 = (unsigned)x0 < (unsigned)WW;
        bool vx1 = (unsigned)x1 < (unsigned)WW;
        int y0c = min(max(y0, 0), HH - 1);
        int y1c = min(max(y1, 0), HH - 1);
        int x0c = min(max(x0, 0), WW - 1);
        int x1c = min(max(x1, 0), WW - 1);

        float w00 = hy * hx * mval * (float)(vy0 && vx0);
        float w01 = hy * lx * mval * (float)(vy0 && vx1);
        float w10 = ly * hx * mval * (float)(vy1 && vx0);
        float w11 = ly * lx * mval * (float)(vy1 && vx1);

        int p00 = (y0c * WW + x0c) * (CC / 4);
        int p01 = (y0c * WW + x1c) * (CC / 4);
        int p10 = (y1c * WW + x0c) * (CC / 4);
        int p11 = (y1c * WW + x1c) * (CC / 4);

#pragma unroll
        for (int j = 0; j < CG / 4; ++j) {
            float4 v00 = xb[p00 + j];
            float4 v01 = xb[p01 + j];
            float4 v10 = xb[p10 + j];
            float4 v11 = xb[p11 + j];
            acc[j].x = fmaf(w00, v00.x, fmaf(w01, v01.x, fmaf(w10, v10.x, fmaf(w11, v11.x, acc[j].x))));
            acc[j].y = fmaf(w00, v00.y, fmaf(w01, v01.y, fmaf(w10, v10.y, fmaf(w11, v11.y, acc[j].y))));
            acc[j].z = fmaf(w00, v00.z, fmaf(w01, v01.z, fmaf(w10, v10.z, fmaf(w11, v11.z, acc[j].z))));
            acc[j].w = fmaf(w00, v00.w, fmaf(w01, v01.w, fmaf(w10, v10.w, fmaf(w11, v11.w, acc[j].w))));
        }
    }

    float* ob = out + ((size_t)b * CC + cq * 4) * HWSZ + hw;
#pragma unroll
    for (int j = 0; j < CG / 4; ++j) {
        ob[(j * 4 + 0) * HWSZ] = acc[j].x;
        ob[(j * 4 + 1) * HWSZ] = acc[j].y;
        ob[(j * 4 + 2) * HWSZ] = acc[j].z;
        ob[(j * 4 + 3) * HWSZ] = acc[j].w;
    }
}

// ---------------- fallback (round-1 kernel, NCHW direct) ----------------
__global__ __launch_bounds__(256, 4) void dcn_kernel(
    const float* __restrict__ x,
    const float* __restrict__ offset,
    const float* __restrict__ mask,
    const float* __restrict__ weight,
    float* __restrict__ out)
{
    const int w   = threadIdx.x;
    const int row = blockIdx.x;
    const int h   = row & (HH - 1);
    const int b   = row >> 8;
    const int c0  = blockIdx.y * CG;
    const int hw  = h * WW + w;

    const float* offb  = offset + (size_t)b * 2 * KK2 * HWSZ + hw;
    const float* maskb = mask   + (size_t)b * KK2 * HWSZ + hw;
    const float* xb0   = x      + ((size_t)b * CC + c0) * HWSZ;

    float acc[CG];
#pragma unroll
    for (int c = 0; c < CG; ++c) acc[c] = 0.f;

    for (int k = 0; k < KK2; ++k) {
        const int ki = k / 3;
        const int kj = k - 3 * ki;
        float offy = offb[(2 * k)     * HWSZ];
        float offx = offb[(2 * k + 1) * HWSZ];
        float mval = maskb[k * HWSZ] * weight[k];

        float py = (float)(h - 1 + ki) + offy;
        float px = (float)(w - 1 + kj) + offx;
        float y0f = floorf(py), x0f = floorf(px);
        float ly = py - y0f, lx = px - x0f;
        float hy = 1.f - ly, hx = 1.f - lx;
        int y0 = (int)y0f, x0 = (int)x0f;
        int y1 = y0 + 1,   x1 = x0 + 1;

        bool vy0 = (unsigned)y0 < (unsigned)HH;
        bool vy1 = (unsigned)y1 < (unsigned)HH;
        bool vx0 = (unsigned)x0 < (unsigned)WW;
        bool vx1 = (unsigned)x1 < (unsigned)WW;
        int y0c = min(max(y0, 0), HH - 1);
        int y1c = min(max(y1, 0), HH - 1);
        int x0c = min(max(x0, 0), WW - 1);
        int x1c = min(max(x1, 0), WW - 1);

        float w00 = hy * hx * mval * (float)(vy0 && vx0);
        float w01 = hy * lx * mval * (float)(vy0 && vx1);
        float w10 = ly * hx * mval * (float)(vy1 && vx0);
        float w11 = ly * lx * mval * (float)(vy1 && vx1);

        int i00 = y0c * WW + x0c;
        int i01 = y0c * WW + x1c;
        int i10 = y1c * WW + x0c;
        int i11 = y1c * WW + x1c;

        const float* xb = xb0;
#pragma unroll
        for (int c = 0; c < CG; ++c) {
            acc[c] = fmaf(w00, xb[i00],
                     fmaf(w01, xb[i01],
                     fmaf(w10, xb[i10],
                     fmaf(w11, xb[i11], acc[c]))));
            xb += HWSZ;
        }
    }

    float* ob = out + ((size_t)b * CC + c0) * HWSZ + hw;
#pragma unroll
    for (int c = 0; c < CG; ++c) ob[c * HWSZ] = acc[c];
}

extern "C" void kernel_launch(void* const* d_in, const int* in_sizes, int n_in,
                              void* d_out, int out_size, void* d_ws, size_t ws_size,
                              hipStream_t stream) {
    const float* x      = (const float*)d_in[0];
    const float* offset = (const float*)d_in[1];
    const float* mask   = (const float*)d_in[2];
    const float* weight = (const float*)d_in[3];
    float* out = (float*)d_out;

    const size_t xT_bytes = (size_t)BB * CC * HWSZ * sizeof(float);
    if (ws_size >= xT_bytes) {
        float* xT = (float*)d_ws;
        dim3 tgrid(BB * HH, WW / 64);
        transpose_nchw_to_nhwc<<<tgrid, 256, 0, stream>>>(x, xT);
        dim3 grid(BB * HH, CC / CG);
        dcn_nhwc<<<grid, 256, 0, stream>>>((const float4*)xT, offset, mask, weight, out);
    } else {
        dim3 grid(BB * HH, CC / CG);
        dcn_kernel<<<grid, 256, 0, stream>>>(x, offset, mask, weight, out);
    }
}

// Round 3
// 77.023 us; speedup vs baseline: 6.1282x; 6.1282x over previous
//
#include <hip/hip_runtime.h>

#define HH 256
#define WW 256
#define CC 64
#define BB 2
#define KK2 9
#define HWSZ (HH * WW)
#define NQ (CC / 4)            // 16 float4 per NHWC pixel

// ---------------- transpose: x[b][c][h][w] -> xT[b][h][w][c] ----------------
__global__ __launch_bounds__(256, 4) void transpose_nchw_to_nhwc(
    const float* __restrict__ x, float* __restrict__ xT)
{
    __shared__ float tile[CC][65];
    const int row = blockIdx.x;
    const int h   = row & (HH - 1);
    const int b   = row >> 8;
    const int w0  = blockIdx.y * 64;
    const int lw  = threadIdx.x & 63;
    const int lr  = threadIdx.x >> 6;

    const float* xp = x + (size_t)b * CC * HWSZ + h * WW + w0;
#pragma unroll
    for (int p = 0; p < 16; ++p) {
        int c = p * 4 + lr;
        tile[c][lw] = xp[(size_t)c * HWSZ + lw];
    }
    __syncthreads();
    float* xo = xT + ((size_t)(b * HH + h) * WW + w0) * CC;
#pragma unroll
    for (int p = 0; p < 16; ++p) {
        int wl = p * 4 + lr;
        xo[wl * CC + lw] = tile[lw][wl];
    }
}

// ---------------- main: NHWC gather, all 64 channels per block ----------------
// 2048 blocks x 256 threads. Block = 64 pixels (quarter row) x all channels.
// lane: p = t>>2 (pixel), jq = t&3 (channel quad phase).
// XCD-chunked swizzle: XCD n owns a contiguous band of rows -> L2 captures
// the +-4-row bilinear reuse window.
__global__ __launch_bounds__(256, 4) void dcn_nhwc2(
    const float4* __restrict__ xT,
    const float* __restrict__ offset,
    const float* __restrict__ mask,
    const float* __restrict__ weight,
    float* __restrict__ out)
{
    const int nblocks = BB * HH * (WW / 64);        // 2048, divisible by 8
    int flat = blockIdx.x;
    int sb   = (flat & 7) * (nblocks >> 3) + (flat >> 3);   // bijective XCD chunk
    int wchunk = sb & 3;
    int row    = sb >> 2;            // 0..511, sequential within an XCD band
    const int h = row & (HH - 1);
    const int b = row >> 8;

    const int t  = threadIdx.x;
    const int jq = t & 3;            // channel-quad phase 0..3
    const int p  = t >> 2;           // pixel within chunk 0..63
    const int w  = (wchunk << 6) + p;
    const int hw = h * WW + w;

    const float* offb  = offset + (size_t)b * 2 * KK2 * HWSZ + hw;
    const float* maskb = mask   + (size_t)b * KK2 * HWSZ + hw;
    const float4* xb   = xT + (size_t)b * HWSZ * NQ;

    float4 acc[4];
#pragma unroll
    for (int j = 0; j < 4; ++j) acc[j] = make_float4(0.f, 0.f, 0.f, 0.f);

#pragma unroll
    for (int k = 0; k < KK2; ++k) {
        const int ki = k / 3;
        const int kj = k - 3 * ki;
        float offy = offb[(2 * k)     * HWSZ];
        float offx = offb[(2 * k + 1) * HWSZ];
        float mval = maskb[k * HWSZ] * weight[k];

        float py = (float)(h - 1 + ki) + offy;
        float px = (float)(w - 1 + kj) + offx;
        float y0f = floorf(py), x0f = floorf(px);
        float ly = py - y0f, lx = px - x0f;
        float hy = 1.f - ly, hx = 1.f - lx;
        int y0 = (int)y0f, x0 = (int)x0f;
        int y1 = y0 + 1,   x1 = x0 + 1;

        bool vy0 = (unsigned)y0 < (unsigned)HH;
        bool vy1 = (unsigned)y1 < (unsigned)HH;
        bool vx0 = (unsigned)x0 < (unsigned)WW;
        bool vx1 = (unsigned)x1 < (unsigned)WW;
        int y0c = min(max(y0, 0), HH - 1);
        int y1c = min(max(y1, 0), HH - 1);
        int x0c = min(max(x0, 0), WW - 1);
        int x1c = min(max(x1, 0), WW - 1);

        float w00 = hy * hx * mval * (float)(vy0 && vx0);
        float w01 = hy * lx * mval * (float)(vy0 && vx1);
        float w10 = ly * hx * mval * (float)(vy1 && vx0);
        float w11 = ly * lx * mval * (float)(vy1 && vx1);

        // float4 base index of each corner pixel, plus this lane's quad phase
        int i00 = (y0c * WW + x0c) * NQ + jq;
        int i01 = (y0c * WW + x1c) * NQ + jq;
        int i10 = (y1c * WW + x0c) * NQ + jq;
        int i11 = (y1c * WW + x1c) * NQ + jq;

#pragma unroll
        for (int j = 0; j < 4; ++j) {
            // lanes 4p..4p+3 read quads 4j..4j+3 => one 64B line per pixel
            float4 v00 = xb[i00 + 4 * j];
            float4 v01 = xb[i01 + 4 * j];
            float4 v10 = xb[i10 + 4 * j];
            float4 v11 = xb[i11 + 4 * j];
            acc[j].x = fmaf(w00, v00.x, fmaf(w01, v01.x, fmaf(w10, v10.x, fmaf(w11, v11.x, acc[j].x))));
            acc[j].y = fmaf(w00, v00.y, fmaf(w01, v01.y, fmaf(w10, v10.y, fmaf(w11, v11.y, acc[j].y))));
            acc[j].z = fmaf(w00, v00.z, fmaf(w01, v01.z, fmaf(w10, v10.z, fmaf(w11, v11.z, acc[j].z))));
            acc[j].w = fmaf(w00, v00.w, fmaf(w01, v01.w, fmaf(w10, v10.w, fmaf(w11, v11.w, acc[j].w))));
        }
    }

    // thread's quad q=4j+jq holds channels 16j + 4jq + e
    float* ob = out + (size_t)b * CC * HWSZ + (size_t)(jq << 2) * HWSZ + hw;
#pragma unroll
    for (int j = 0; j < 4; ++j) {
        ob[(16 * j + 0) * HWSZ] = acc[j].x;
        ob[(16 * j + 1) * HWSZ] = acc[j].y;
        ob[(16 * j + 2) * HWSZ] = acc[j].z;
        ob[(16 * j + 3) * HWSZ] = acc[j].w;
    }
}

// ---------------- fallback (NCHW direct, round-1) ----------------
__global__ __launch_bounds__(256, 4) void dcn_kernel(
    const float* __restrict__ x,
    const float* __restrict__ offset,
    const float* __restrict__ mask,
    const float* __restrict__ weight,
    float* __restrict__ out)
{
    const int w   = threadIdx.x;
    const int row = blockIdx.x;
    const int h   = row & (HH - 1);
    const int b   = row >> 8;
    const int c0  = blockIdx.y * 16;
    const int hw  = h * WW + w;

    const float* offb  = offset + (size_t)b * 2 * KK2 * HWSZ + hw;
    const float* maskb = mask   + (size_t)b * KK2 * HWSZ + hw;
    const float* xb0   = x      + ((size_t)b * CC + c0) * HWSZ;

    float acc[16];
#pragma unroll
    for (int c = 0; c < 16; ++c) acc[c] = 0.f;

    for (int k = 0; k < KK2; ++k) {
        const int ki = k / 3;
        const int kj = k - 3 * ki;
        float offy = offb[(2 * k)     * HWSZ];
        float offx = offb[(2 * k + 1) * HWSZ];
        float mval = maskb[k * HWSZ] * weight[k];

        float py = (float)(h - 1 + ki) + offy;
        float px = (float)(w - 1 + kj) + offx;
        float y0f = floorf(py), x0f = floorf(px);
        float ly = py - y0f, lx = px - x0f;
        float hy = 1.f - ly, hx = 1.f - lx;
        int y0 = (int)y0f, x0 = (int)x0f;
        int y1 = y0 + 1,   x1 = x0 + 1;

        bool vy0 = (unsigned)y0 < (unsigned)HH;
        bool vy1 = (unsigned)y1 < (unsigned)HH;
        bool vx0 = (unsigned)x0 < (unsigned)WW;
        bool vx1 = (unsigned)x1 < (unsigned)WW;
        int y0c = min(max(y0, 0), HH - 1);
        int y1c = min(max(y1, 0), HH - 1);
        int x0c = min(max(x0, 0), WW - 1);
        int x1c = min(max(x1, 0), WW - 1);

        float w00 = hy * hx * mval * (float)(vy0 && vx0);
        float w01 = hy * lx * mval * (float)(vy0 && vx1);
        float w10 = ly * hx * mval * (float)(vy1 && vx0);
        float w11 = ly * lx * mval * (float)(vy1 && vx1);

        int i00 = y0c * WW + x0c;
        int i01 = y0c * WW + x1c;
        int i10 = y1c * WW + x0c;
        int i11 = y1c * WW + x1c;

        const float* xb = xb0;
#pragma unroll
        for (int c = 0; c < 16; ++c) {
            acc[c] = fmaf(w00, xb[i00],
                     fmaf(w01, xb[i01],
                     fmaf(w10, xb[i10],
                     fmaf(w11, xb[i11], acc[c]))));
            xb += HWSZ;
        }
    }

    float* ob = out + ((size_t)b * CC + c0) * HWSZ + hw;
#pragma unroll
    for (int c = 0; c < 16; ++c) ob[c * HWSZ] = acc[c];
}

extern "C" void kernel_launch(void* const* d_in, const int* in_sizes, int n_in,
                              void* d_out, int out_size, void* d_ws, size_t ws_size,
                              hipStream_t stream) {
    const float* x      = (const float*)d_in[0];
    const float* offset = (const float*)d_in[1];
    const float* mask   = (const float*)d_in[2];
    const float* weight = (const float*)d_in[3];
    float* out = (float*)d_out;

    const size_t xT_bytes = (size_t)BB * CC * HWSZ * sizeof(float);
    if (ws_size >= xT_bytes) {
        float* xT = (float*)d_ws;
        dim3 tgrid(BB * HH, WW / 64);
        transpose_nchw_to_nhwc<<<tgrid, 256, 0, stream>>>(x, xT);
        dcn_nhwc2<<<BB * HH * (WW / 64), 256, 0, stream>>>(
            (const float4*)xT, offset, mask, weight, out);
    } else {
        dim3 grid(BB * HH, CC / 16);
        dcn_kernel<<<grid, 256, 0, stream>>>(x, offset, mask, weight, out);
    }
}